// Round 2
// baseline (14929.356 us; speedup 1.0000x reference)
//
#include <hip/hip_runtime.h>

// LearnableCell: FiLM'd LayerNorm-GRU.
// Two-kernel decomposition:
//   K1 inproj  (parallel over B*T): ih_all = LN(x @ Wx^T + bx) * alpha_i + beta_i -> d_ws
//   K2 gru_rec (serial over T, 32 WGs): thread j owns gate rows {j, j+128, j+256}
//      -> gates thread-local, 2 barriers/step, h broadcast via LDS, DPP reduce.
// Fallback: round-1 monolithic kernel if ws_size too small.

#define T_STEPS 8192
#define BATCH   32
#define HDIM    128
#define GDIM    384
#define IDIM    16
#define LN_EPS  1e-5f

typedef float f32x2 __attribute__((ext_vector_type(2)));
typedef float f32x4 __attribute__((ext_vector_type(4)));

__device__ __forceinline__ void block_barrier() {
  asm volatile("s_waitcnt lgkmcnt(0)\n\ts_barrier" ::: "memory");
}

__device__ __forceinline__ float fast_sigmoid(float x) {
  return 1.f / (1.f + __expf(-x));
}
__device__ __forceinline__ float fast_tanh(float x) {
  float e2 = __expf(2.f * x);
  return 1.f - 2.f / (e2 + 1.f);
}

// one DPP xor-add level (row-local, 16-lane groups)
template <int CTRL>
__device__ __forceinline__ float dppadd(float x) {
  return x + __int_as_float(
      __builtin_amdgcn_update_dpp(0, __float_as_int(x), CTRL, 0xF, 0xF, true));
}
// full sum over each 16-lane group (xor 1,2,4,8)
__device__ __forceinline__ float dpp_sum16(float x) {
  x = dppadd<0xB1>(x);   // quad_perm [1,0,3,2]  (xor 1)
  x = dppadd<0x4E>(x);   // quad_perm [2,3,0,1]  (xor 2)
  x = dppadd<0x141>(x);  // row_half_mirror      (xor 4)
  x = dppadd<0x140>(x);  // row_mirror           (xor 8)
  return x;
}

// ---------------- K1: input projection + LN + FiLM (parallel over B*T) -------
__global__ __launch_bounds__(256) void inproj(
    const float* __restrict__ xs,       // [B,T,I]
    const float* __restrict__ alpha_i,  // [B,G]
    const float* __restrict__ beta_i,   // [B,G]
    const float* __restrict__ Wx,       // [G,I]
    const float* __restrict__ bx,       // [G]
    float* __restrict__ ih_all)         // [B,T,G]
{
  const int wid  = threadIdx.x >> 6;
  const int lane = threadIdx.x & 63;
  const size_t w = (size_t)blockIdx.x * 4 + wid;  // [0, B*T)
  const int b = (int)(w >> 13);                   // / 8192
  // x[b,t,:] : 16 floats, broadcast
  const f32x4* xp = (const f32x4*)(xs + w * IDIM);
  f32x4 x0 = xp[0], x1 = xp[1], x2 = xp[2], x3 = xp[3];

  float acc[6];
  float s = 0.f, s2 = 0.f;
#pragma unroll
  for (int k = 0; k < 6; ++k) {
    const int g = k * 64 + lane;
    const f32x4* wp = (const f32x4*)(Wx + (size_t)g * IDIM);
    f32x4 a = __builtin_elementwise_fma(wp[0], x0, (f32x4){0.f, 0.f, 0.f, 0.f});
    a = __builtin_elementwise_fma(wp[1], x1, a);
    a = __builtin_elementwise_fma(wp[2], x2, a);
    a = __builtin_elementwise_fma(wp[3], x3, a);
    float v = bx[g] + ((a.x + a.y) + (a.z + a.w));
    acc[k] = v;
    s += v;
    s2 += v * v;
  }
  // LN over 384 within the wave: dpp to 16-groups, then xor 16, 32
  s  = dpp_sum16(s);
  s2 = dpp_sum16(s2);
  s  += __shfl_xor(s, 16);  s2 += __shfl_xor(s2, 16);
  s  += __shfl_xor(s, 32);  s2 += __shfl_xor(s2, 32);

  const float inv = 1.f / (float)GDIM;
  const float m = s * inv;
  const float r = rsqrtf(s2 * inv - m * m + LN_EPS);

  float* op = ih_all + w * GDIM;
  const float* ai = alpha_i + (size_t)b * GDIM;
  const float* bi = beta_i + (size_t)b * GDIM;
#pragma unroll
  for (int k = 0; k < 6; ++k) {
    const int g = k * 64 + lane;
    op[g] = (acc[k] - m) * r * ai[g] + bi[g];
  }
}

// ---------------- K2: serial recurrence, 128 threads / chain -----------------
__global__ __launch_bounds__(HDIM, 1) void gru_rec(
    const float* __restrict__ state,    // [1,B,H]
    const float* __restrict__ alpha_h,  // [B,G]
    const float* __restrict__ beta_h,   // [B,G]
    const float* __restrict__ Wh,       // [G,H]
    const float* __restrict__ bh,       // [G]
    const float* __restrict__ ih_all,   // [B,T,G]
    float* __restrict__ out)            // [B,T,H] then [B,1,H]
{
  __shared__ float lds_h[HDIM];
  __shared__ __align__(16) f32x2 lds_red[8];

  const int b = blockIdx.x;
  const int j = threadIdx.x;  // hidden unit, 0..127

  // rows: r=j, i=j+128, n=j+256
  f32x4 wr[HDIM / 4], wi[HDIM / 4], wn[HDIM / 4];
#pragma unroll
  for (int q = 0; q < HDIM / 4; ++q) {
    wr[q] = ((const f32x4*)(Wh + (size_t)j * HDIM))[q];
    wi[q] = ((const f32x4*)(Wh + (size_t)(j + HDIM) * HDIM))[q];
    wn[q] = ((const f32x4*)(Wh + (size_t)(j + 2 * HDIM) * HDIM))[q];
  }
  const float bh_r = bh[j], bh_i = bh[j + HDIM], bh_n = bh[j + 2 * HDIM];
  const float ah_r = alpha_h[b * GDIM + j];
  const float ah_i = alpha_h[b * GDIM + j + HDIM];
  const float ah_n = alpha_h[b * GDIM + j + 2 * HDIM];
  const float bt_r = beta_h[b * GDIM + j];
  const float bt_i = beta_h[b * GDIM + j + HDIM];
  const float bt_n = beta_h[b * GDIM + j + 2 * HDIM];

  float hreg = state[b * HDIM + j];
  lds_h[j] = hreg;

  const float* ih_b = ih_all + (size_t)b * T_STEPS * GDIM;
  float* out_b = out + (size_t)b * T_STEPS * HDIM;

  // prefetch sets A (t), B (t+1)
  float irA = ih_b[j],            iiA = ih_b[j + HDIM],            inA = ih_b[j + 2 * HDIM];
  float irB = ih_b[GDIM + j],     iiB = ih_b[GDIM + j + HDIM],     inB = ih_b[GDIM + j + 2 * HDIM];
  block_barrier();

#define STEP(tcur, IR, II, IN_)                                                \
  do {                                                                         \
    const f32x4* hb = (const f32x4*)lds_h;                                     \
    f32x4 a0r = {0.f, 0.f, 0.f, 0.f}, a1r = a0r;                               \
    f32x4 a0i = a0r, a1i = a0r, a0n = a0r, a1n = a0r;                          \
    _Pragma("unroll") for (int q = 0; q < HDIM / 4; q += 2) {                  \
      f32x4 h0 = hb[q], h1 = hb[q + 1];                                        \
      a0r = __builtin_elementwise_fma(wr[q], h0, a0r);                         \
      a1r = __builtin_elementwise_fma(wr[q + 1], h1, a1r);                     \
      a0i = __builtin_elementwise_fma(wi[q], h0, a0i);                         \
      a1i = __builtin_elementwise_fma(wi[q + 1], h1, a1i);                     \
      a0n = __builtin_elementwise_fma(wn[q], h0, a0n);                         \
      a1n = __builtin_elementwise_fma(wn[q + 1], h1, a1n);                     \
    }                                                                          \
    a0r += a1r; a0i += a1i; a0n += a1n;                                        \
    float accr = bh_r + ((a0r.x + a0r.y) + (a0r.z + a0r.w));                   \
    float acci = bh_i + ((a0i.x + a0i.y) + (a0i.z + a0i.w));                   \
    float accn = bh_n + ((a0n.x + a0n.y) + (a0n.z + a0n.w));                   \
    float s  = accr + acci + accn;                                             \
    float s2 = accr * accr + acci * acci + accn * accn;                        \
    s = dpp_sum16(s);                                                          \
    s2 = dpp_sum16(s2);                                                        \
    if ((j & 15) == 0) lds_red[j >> 4] = (f32x2){s, s2};                       \
    block_barrier();                                                           \
    const f32x4* rp = (const f32x4*)lds_red;                                   \
    f32x4 rs = rp[0] + rp[1] + rp[2] + rp[3];                                  \
    float S = rs.x + rs.z, S2 = rs.y + rs.w;                                   \
    const float inv = 1.f / (float)GDIM;                                       \
    float m = S * inv;                                                         \
    float rstd = rsqrtf(S2 * inv - m * m + LN_EPS);                            \
    float hh_r = (accr - m) * rstd * ah_r + bt_r;                              \
    float hh_i = (acci - m) * rstd * ah_i + bt_i;                              \
    float hh_n = (accn - m) * rstd * ah_n + bt_n;                              \
    float rg = fast_sigmoid(IR + hh_r);                                        \
    float ig = fast_sigmoid(II + hh_i);                                        \
    float ng = fast_tanh(IN_ + rg * hh_n);                                     \
    float hy = ng + ig * (hreg - ng);                                          \
    hreg = hy;                                                                 \
    lds_h[j] = hy;                                                             \
    out_b[(size_t)(tcur)*HDIM + j] = hy;                                       \
    int tn = (tcur) + 2 < T_STEPS ? (tcur) + 2 : T_STEPS - 1;                  \
    const float* pp = ih_b + (size_t)tn * GDIM;                                \
    IR = pp[j]; II = pp[j + HDIM]; IN_ = pp[j + 2 * HDIM];                     \
    block_barrier();                                                           \
  } while (0)

  for (int t = 0; t < T_STEPS; t += 2) {
    STEP(t, irA, iiA, inA);
    STEP(t + 1, irB, iiB, inB);
  }
#undef STEP

  out[(size_t)BATCH * T_STEPS * HDIM + b * HDIM + j] = hreg;
}

// ---------------- Fallback: round-1 monolithic kernel (verified) -------------
__global__ __launch_bounds__(GDIM, 1) void gru_fused(
    const float* __restrict__ xs, const float* __restrict__ state,
    const float* __restrict__ alpha_i, const float* __restrict__ beta_i,
    const float* __restrict__ alpha_h, const float* __restrict__ beta_h,
    const float* __restrict__ Wx, const float* __restrict__ bx,
    const float* __restrict__ Wh, const float* __restrict__ bh,
    float* __restrict__ out)
{
  __shared__ float lds_h[HDIM];
  __shared__ float lds_hh[GDIM];
  __shared__ float lds_ih[GDIM];
  __shared__ float lds_x[2][IDIM];
  __shared__ f32x4 lds_red[GDIM / 64];

  const int b = blockIdx.x;
  const int g = threadIdx.x;
  const int wid = g >> 6;
  const int lane = g & 63;

  f32x4 wh4[HDIM / 4];
#pragma unroll
  for (int i = 0; i < HDIM / 4; ++i)
    wh4[i] = ((const f32x4*)(Wh + (size_t)g * HDIM))[i];
  f32x4 wx4[IDIM / 4];
#pragma unroll
  for (int i = 0; i < IDIM / 4; ++i)
    wx4[i] = ((const f32x4*)(Wx + (size_t)g * IDIM))[i];

  const float bxg = bx[g];
  const float bhg = bh[g];
  const float aig = alpha_i[b * GDIM + g];
  const float big = beta_i[b * GDIM + g];
  const float ahg = alpha_h[b * GDIM + g];
  const float bhg2 = beta_h[b * GDIM + g];

  const float* xs_b = xs + (size_t)b * T_STEPS * IDIM;

  if (g < HDIM) lds_h[g] = state[b * HDIM + g];
  if (g < IDIM) lds_x[0][g] = xs_b[g];
  float xpre = (g < IDIM) ? xs_b[IDIM + g] : 0.f;
  block_barrier();

  float* out_b = out + (size_t)b * T_STEPS * HDIM;

  for (int t = 0; t < T_STEPS; ++t) {
    const f32x4* xb = (const f32x4*)lds_x[t & 1];
    f32x4 aI = {0.f, 0.f, 0.f, 0.f};
#pragma unroll
    for (int i = 0; i < IDIM / 4; ++i)
      aI = __builtin_elementwise_fma(wx4[i], xb[i], aI);
    float accI = bxg + ((aI.x + aI.y) + (aI.z + aI.w));

    const f32x4* hb = (const f32x4*)lds_h;
    f32x4 aH0 = {0.f, 0.f, 0.f, 0.f};
    f32x4 aH1 = {0.f, 0.f, 0.f, 0.f};
#pragma unroll
    for (int i = 0; i < HDIM / 4; i += 2) {
      aH0 = __builtin_elementwise_fma(wh4[i], hb[i], aH0);
      aH1 = __builtin_elementwise_fma(wh4[i + 1], hb[i + 1], aH1);
    }
    f32x4 aH = aH0 + aH1;
    float accH = bhg + ((aH.x + aH.y) + (aH.z + aH.w));

    f32x4 red = {accI, accI * accI, accH, accH * accH};
#pragma unroll
    for (int m = 32; m >= 1; m >>= 1) {
      f32x4 o;
      o.x = __shfl_xor(red.x, m);
      o.y = __shfl_xor(red.y, m);
      o.z = __shfl_xor(red.z, m);
      o.w = __shfl_xor(red.w, m);
      red += o;
    }
    if (lane == 0) lds_red[wid] = red;
    block_barrier();
    f32x4 s = lds_red[0];
#pragma unroll
    for (int w = 1; w < GDIM / 64; ++w) s += lds_red[w];

    const float inv = 1.f / (float)GDIM;
    float mI = s.x * inv;
    float rI = rsqrtf(s.y * inv - mI * mI + LN_EPS);
    float mH = s.z * inv;
    float rH = rsqrtf(s.w * inv - mH * mH + LN_EPS);

    float ihg = (accI - mI) * rI * aig + big;
    float hhg = (accH - mH) * rH * ahg + bhg2;
    lds_ih[g] = ihg;
    lds_hh[g] = hhg;
    block_barrier();

    if (g < IDIM) {
      lds_x[(t + 1) & 1][g] = xpre;
      int tn = (t + 2 < T_STEPS) ? (t + 2) : t;
      xpre = xs_b[(size_t)tn * IDIM + g];
    }

    if (g < HDIM) {
      float hr = lds_hh[g];
      float hi = lds_hh[g + HDIM];
      float hn = lds_hh[g + 2 * HDIM];
      float ir = lds_ih[g];
      float ii = lds_ih[g + HDIM];
      float in_ = lds_ih[g + 2 * HDIM];

      float resetg = fast_sigmoid(ir + hr);
      float inputg = fast_sigmoid(ii + hi);
      float newg = fast_tanh(in_ + resetg * hn);
      float hold = lds_h[g];
      float hy = newg + inputg * (hold - newg);

      lds_h[g] = hy;
      out_b[(size_t)t * HDIM + g] = hy;
    }
    block_barrier();
  }

  if (g < HDIM)
    out[(size_t)BATCH * T_STEPS * HDIM + b * HDIM + g] = lds_h[g];
}

extern "C" void kernel_launch(void* const* d_in, const int* in_sizes, int n_in,
                              void* d_out, int out_size, void* d_ws, size_t ws_size,
                              hipStream_t stream) {
  const float* xs      = (const float*)d_in[0];
  const float* state   = (const float*)d_in[1];
  const float* alpha_i = (const float*)d_in[2];
  const float* beta_i  = (const float*)d_in[3];
  const float* alpha_h = (const float*)d_in[4];
  const float* beta_h  = (const float*)d_in[5];
  const float* Wx      = (const float*)d_in[6];
  const float* bx      = (const float*)d_in[7];
  const float* Wh      = (const float*)d_in[8];
  const float* bh      = (const float*)d_in[9];
  float* out = (float*)d_out;

  const size_t ih_bytes = (size_t)BATCH * T_STEPS * GDIM * sizeof(float);
  if (ws_size >= ih_bytes) {
    float* ih_all = (float*)d_ws;
    inproj<<<dim3(BATCH * T_STEPS / 4), dim3(256), 0, stream>>>(
        xs, alpha_i, beta_i, Wx, bx, ih_all);
    gru_rec<<<dim3(BATCH), dim3(HDIM), 0, stream>>>(
        state, alpha_h, beta_h, Wh, bh, ih_all, out);
  } else {
    gru_fused<<<dim3(BATCH), dim3(GDIM), 0, stream>>>(
        xs, state, alpha_i, beta_i, alpha_h, beta_h, Wx, bx, Wh, bh, out);
  }
}

// Round 3
// 11705.345 us; speedup vs baseline: 1.2754x; 1.2754x over previous
//
#include <hip/hip_runtime.h>

// LearnableCell: FiLM'd LayerNorm-GRU, single fused kernel, round 3.
// 32 WGs (one per batch chain) x 256 threads (4 waves).
// Thread t: j = t&127 (hidden unit), half = t>>7 (K-split of the h-dim).
// Owns gate rows {j, j+128, j+256} for h-cols [half*64, half*64+64) -> 192
// weight VGPRs, forced resident via inline-asm keep-alive (round-2 post-mortem:
// compiler rematerialized weight loads every step -> VMEM-bound, VGPR_Count=224).
// Per step: K-split matvec -> partner exchange (packed 6 floats) -> wave reduce
// (DPP + shfl) -> joint LN stats (x2-counted, /768) -> FiLM -> gates -> h.
// 3 barriers/step, none draining vmcnt (out-stores / x-prefetch stay in flight).

#define T_STEPS 8192
#define BATCH   32
#define HDIM    128
#define GDIM    384
#define IDIM    16
#define LN_EPS  1e-5f

typedef float f32x2 __attribute__((ext_vector_type(2)));
typedef float f32x4 __attribute__((ext_vector_type(4)));

__device__ __forceinline__ void block_barrier() {
  asm volatile("s_waitcnt lgkmcnt(0)\n\ts_barrier" ::: "memory");
}

__device__ __forceinline__ float fast_sigmoid(float x) {
  return 1.f / (1.f + __expf(-x));
}
__device__ __forceinline__ float fast_tanh(float x) {
  float e2 = __expf(2.f * x);
  return 1.f - 2.f / (e2 + 1.f);
}
__device__ __forceinline__ float hsum4(f32x4 v) {
  return (v.x + v.y) + (v.z + v.w);
}

// one DPP xor-add level within 16-lane rows
template <int CTRL>
__device__ __forceinline__ float dppadd(float x) {
  return x + __int_as_float(
      __builtin_amdgcn_update_dpp(0, __float_as_int(x), CTRL, 0xF, 0xF, true));
}
__device__ __forceinline__ float dpp_sum16(float x) {
  x = dppadd<0xB1>(x);   // xor 1
  x = dppadd<0x4E>(x);   // xor 2
  x = dppadd<0x141>(x);  // xor 4 (row_half_mirror)
  x = dppadd<0x140>(x);  // xor 8 (row_mirror)
  return x;
}
// full 64-lane sum of 4 components
__device__ __forceinline__ f32x4 wave_sum(f32x4 v) {
  v.x = dpp_sum16(v.x); v.y = dpp_sum16(v.y);
  v.z = dpp_sum16(v.z); v.w = dpp_sum16(v.w);
  v.x += __shfl_xor(v.x, 16); v.y += __shfl_xor(v.y, 16);
  v.z += __shfl_xor(v.z, 16); v.w += __shfl_xor(v.w, 16);
  v.x += __shfl_xor(v.x, 32); v.y += __shfl_xor(v.y, 32);
  v.z += __shfl_xor(v.z, 32); v.w += __shfl_xor(v.w, 32);
  return v;
}

__global__ __launch_bounds__(256, 1) void gru_one(
    const float* __restrict__ xs,       // [B,T,I]
    const float* __restrict__ state,    // [1,B,H]
    const float* __restrict__ alpha_i,  // [B,G]
    const float* __restrict__ beta_i,   // [B,G]
    const float* __restrict__ alpha_h,  // [B,G]
    const float* __restrict__ beta_h,   // [B,G]
    const float* __restrict__ Wx,       // [G,I]
    const float* __restrict__ bx,       // [G]
    const float* __restrict__ Wh,       // [G,H]
    const float* __restrict__ bh,       // [G]
    float* __restrict__ out)            // [B,T,H] then [B,1,H]
{
  __shared__ float lds_h[HDIM];
  __shared__ __align__(16) f32x4 lds_pA[256];  // {Hr,Hi,Hn,Ir} partials
  __shared__ __align__(16) f32x2 lds_pB[256];  // {Ii,In} partials
  __shared__ __align__(16) f32x4 lds_stat[4];  // per-wave {sH,sH2,sI,sI2}

  const int b    = blockIdx.x;
  const int t_   = threadIdx.x;
  const int j    = t_ & 127;
  const int half = t_ >> 7;
  const int lane = t_ & 63;
  const int wv   = t_ >> 6;

  const int rowR = j, rowI = j + HDIM, rowN = j + 2 * HDIM;

  // ---- persistent weights: Wh rows {R,I,N}, cols [half*64, half*64+64) ----
  f32x4 wr[16], wi[16], wn[16];
  {
    const f32x4* pr = (const f32x4*)(Wh + (size_t)rowR * HDIM + half * 64);
    const f32x4* pi = (const f32x4*)(Wh + (size_t)rowI * HDIM + half * 64);
    const f32x4* pn = (const f32x4*)(Wh + (size_t)rowN * HDIM + half * 64);
#pragma unroll
    for (int q = 0; q < 16; ++q) { wr[q] = pr[q]; wi[q] = pi[q]; wn[q] = pn[q]; }
  }
  // Wx rows {R,I,N}, cols [half*8, half*8+8)
  f32x4 wxr[2], wxi[2], wxn[2];
  {
    const f32x4* pr = (const f32x4*)(Wx + (size_t)rowR * IDIM + half * 8);
    const f32x4* pi = (const f32x4*)(Wx + (size_t)rowI * IDIM + half * 8);
    const f32x4* pn = (const f32x4*)(Wx + (size_t)rowN * IDIM + half * 8);
#pragma unroll
    for (int q = 0; q < 2; ++q) { wxr[q] = pr[q]; wxi[q] = pi[q]; wxn[q] = pn[q]; }
  }
  // Force residency: opaque asm ties -> compiler cannot rematerialize via reload.
#pragma unroll
  for (int q = 0; q < 16; ++q)
    asm volatile("" : "+v"(wr[q]), "+v"(wi[q]), "+v"(wn[q]));
#pragma unroll
  for (int q = 0; q < 2; ++q)
    asm volatile("" : "+v"(wxr[q]), "+v"(wxi[q]), "+v"(wxn[q]));

  // ---- per-thread scalars ----
  const float bh_r = bh[rowR], bh_i = bh[rowI], bh_n = bh[rowN];
  const float bx_r = bx[rowR], bx_i = bx[rowI], bx_n = bx[rowN];
  const float ah_r = alpha_h[b * GDIM + rowR];
  const float ah_i = alpha_h[b * GDIM + rowI];
  const float ah_n = alpha_h[b * GDIM + rowN];
  const float bt_r = beta_h[b * GDIM + rowR];
  const float bt_i = beta_h[b * GDIM + rowI];
  const float bt_n = beta_h[b * GDIM + rowN];
  const float ai_r = alpha_i[b * GDIM + rowR];
  const float ai_i = alpha_i[b * GDIM + rowI];
  const float ai_n = alpha_i[b * GDIM + rowN];
  const float bi_r = beta_i[b * GDIM + rowR];
  const float bi_i = beta_i[b * GDIM + rowI];
  const float bi_n = beta_i[b * GDIM + rowN];

  float hreg = state[b * HDIM + j];
  if (t_ < HDIM) lds_h[j] = hreg;

  const f32x4* xp = (const f32x4*)(xs + (size_t)b * T_STEPS * IDIM);
  float* out_b = out + (size_t)b * T_STEPS * HDIM;

  // x prefetch: set A = t, set B = t+1; each set = this thread's 8 cols.
  f32x4 xA0 = xp[half * 2],     xA1 = xp[half * 2 + 1];
  f32x4 xB0 = xp[4 + half * 2], xB1 = xp[4 + half * 2 + 1];

  const float invd = 1.f / (2.f * (float)GDIM);  // stats are double-counted

#define STEP(tcur, X0, X1)                                                     \
  do {                                                                         \
    block_barrier(); /* A: h published */                                      \
    const f32x4* hb = ((const f32x4*)lds_h) + half * 16;                       \
    f32x4 pr0 = {0.f, 0.f, 0.f, 0.f}, pr1 = pr0;                               \
    f32x4 pi0 = pr0, pi1 = pr0, pn0 = pr0, pn1 = pr0;                          \
    _Pragma("unroll") for (int q = 0; q < 16; q += 2) {                        \
      f32x4 h0 = hb[q], h1 = hb[q + 1];                                        \
      pr0 = __builtin_elementwise_fma(wr[q], h0, pr0);                         \
      pr1 = __builtin_elementwise_fma(wr[q + 1], h1, pr1);                     \
      pi0 = __builtin_elementwise_fma(wi[q], h0, pi0);                         \
      pi1 = __builtin_elementwise_fma(wi[q + 1], h1, pi1);                     \
      pn0 = __builtin_elementwise_fma(wn[q], h0, pn0);                         \
      pn1 = __builtin_elementwise_fma(wn[q + 1], h1, pn1);                     \
    }                                                                          \
    float accr = hsum4(pr0 + pr1);                                             \
    float acci = hsum4(pi0 + pi1);                                             \
    float accn = hsum4(pn0 + pn1);                                             \
    f32x4 qr = __builtin_elementwise_fma(                                      \
        wxr[0], X0, (f32x4){0.f, 0.f, 0.f, 0.f});                              \
    qr = __builtin_elementwise_fma(wxr[1], X1, qr);                            \
    f32x4 qi = __builtin_elementwise_fma(                                      \
        wxi[0], X0, (f32x4){0.f, 0.f, 0.f, 0.f});                              \
    qi = __builtin_elementwise_fma(wxi[1], X1, qi);                            \
    f32x4 qn = __builtin_elementwise_fma(                                      \
        wxn[0], X0, (f32x4){0.f, 0.f, 0.f, 0.f});                              \
    qn = __builtin_elementwise_fma(wxn[1], X1, qn);                            \
    float aIr = hsum4(qr), aIi = hsum4(qi), aIn = hsum4(qn);                   \
    lds_pA[t_] = (f32x4){accr, acci, accn, aIr};                               \
    lds_pB[t_] = (f32x2){aIi, aIn};                                            \
    block_barrier(); /* B: partials published */                               \
    f32x4 oA = lds_pA[t_ ^ 128];                                               \
    f32x2 oB = lds_pB[t_ ^ 128];                                               \
    float Ar = accr + oA.x + bh_r;                                             \
    float Ai = acci + oA.y + bh_i;                                             \
    float An = accn + oA.z + bh_n;                                             \
    float Jr = aIr + oA.w + bx_r;                                              \
    float Ji = aIi + oB.x + bx_i;                                              \
    float Jn = aIn + oB.y + bx_n;                                              \
    f32x4 st = {Ar + Ai + An, Ar * Ar + Ai * Ai + An * An,                     \
                Jr + Ji + Jn, Jr * Jr + Ji * Ji + Jn * Jn};                    \
    st = wave_sum(st);                                                         \
    if (lane == 0) lds_stat[wv] = st;                                          \
    block_barrier(); /* C: stats published */                                  \
    f32x4 sT = (lds_stat[0] + lds_stat[1]) + (lds_stat[2] + lds_stat[3]);      \
    float mH = sT.x * invd;                                                    \
    float rH = rsqrtf(sT.y * invd - mH * mH + LN_EPS);                         \
    float mI = sT.z * invd;                                                    \
    float rI = rsqrtf(sT.w * invd - mI * mI + LN_EPS);                         \
    float hhr = (Ar - mH) * rH * ah_r + bt_r;                                  \
    float hhi = (Ai - mH) * rH * ah_i + bt_i;                                  \
    float hhn = (An - mH) * rH * ah_n + bt_n;                                  \
    float ihr = (Jr - mI) * rI * ai_r + bi_r;                                  \
    float ihi = (Ji - mI) * rI * ai_i + bi_i;                                  \
    float ihn = (Jn - mI) * rI * ai_n + bi_n;                                  \
    float rg = fast_sigmoid(ihr + hhr);                                       \
    float ig = fast_sigmoid(ihi + hhi);                                       \
    float ng = fast_tanh(ihn + rg * hhn);                                     \
    float hy = ng + ig * (hreg - ng);                                          \
    hreg = hy;                                                                 \
    if (t_ < HDIM) {                                                           \
      lds_h[j] = hy;                                                           \
      out_b[(size_t)(tcur) * HDIM + j] = hy;                                   \
    }                                                                          \
    int tn = (tcur) + 2 < T_STEPS ? (tcur) + 2 : T_STEPS - 1;                  \
    X0 = xp[(size_t)tn * 4 + half * 2];                                        \
    X1 = xp[(size_t)tn * 4 + half * 2 + 1];                                    \
  } while (0)

  for (int t = 0; t < T_STEPS; t += 2) {
    STEP(t, xA0, xA1);
    STEP(t + 1, xB0, xB1);
  }
#undef STEP

  if (t_ < HDIM)
    out[(size_t)BATCH * T_STEPS * HDIM + b * HDIM + j] = hreg;
}

extern "C" void kernel_launch(void* const* d_in, const int* in_sizes, int n_in,
                              void* d_out, int out_size, void* d_ws, size_t ws_size,
                              hipStream_t stream) {
  const float* xs      = (const float*)d_in[0];
  const float* state   = (const float*)d_in[1];
  const float* alpha_i = (const float*)d_in[2];
  const float* beta_i  = (const float*)d_in[3];
  const float* alpha_h = (const float*)d_in[4];
  const float* beta_h  = (const float*)d_in[5];
  const float* Wx      = (const float*)d_in[6];
  const float* bx      = (const float*)d_in[7];
  const float* Wh      = (const float*)d_in[8];
  const float* bh      = (const float*)d_in[9];
  float* out = (float*)d_out;

  gru_one<<<dim3(BATCH), dim3(256), 0, stream>>>(
      xs, state, alpha_i, beta_i, alpha_h, beta_h, Wx, bx, Wh, bh, out);
}

// Round 4
// 11093.336 us; speedup vs baseline: 1.3458x; 1.0552x over previous
//
#include <hip/hip_runtime.h>

// LearnableCell: FiLM'd LayerNorm-GRU, single fused kernel, round 4.
// 32 WGs (one per batch chain) x 512 threads (8 waves, 2 waves/SIMD).
// Thread (wave w, lane l): j = w*16 + (l&15)  (hidden unit 0..127)
//                          q = l>>4           (K-quarter: h-cols [q*32,q*32+32))
// Owns gate rows {j, j+128, j+256} for its 32 cols -> 96 weight VGPRs + 12 Wx,
// produced through opaque asm so they cannot be rematerialized (rounds 1-3:
// compiler re-fetched weights every step -> VMEM-latency bound, VGPR<=152).
// Per step: matvec -> in-wave K-combine (shfl_xor 16/32) -> DPP LN stats ->
// 8 wave-partials in LDS -> LN + FiLM + gates (replicated x4) -> h publish.
// 2 barriers/step, none draining vmcnt (out-stores & x-prefetch stay in flight).

#define T_STEPS 8192
#define BATCH   32
#define HDIM    128
#define GDIM    384
#define IDIM    16
#define LN_EPS  1e-5f
#define NT      512

typedef float f32x2 __attribute__((ext_vector_type(2)));
typedef float f32x4 __attribute__((ext_vector_type(4)));

__device__ __forceinline__ void block_barrier() {
  asm volatile("s_waitcnt lgkmcnt(0)\n\ts_barrier" ::: "memory");
}

__device__ __forceinline__ float fast_sigmoid(float x) {
  return 1.f / (1.f + __expf(-x));
}
__device__ __forceinline__ float fast_tanh(float x) {
  float e2 = __expf(2.f * x);
  return 1.f - 2.f / (e2 + 1.f);
}
__device__ __forceinline__ float hsum4(f32x4 v) {
  return (v.x + v.y) + (v.z + v.w);
}

template <int CTRL>
__device__ __forceinline__ float dppadd(float x) {
  return x + __int_as_float(
      __builtin_amdgcn_update_dpp(0, __float_as_int(x), CTRL, 0xF, 0xF, true));
}
__device__ __forceinline__ float dpp_sum16(float x) {
  x = dppadd<0xB1>(x);   // xor 1
  x = dppadd<0x4E>(x);   // xor 2
  x = dppadd<0x141>(x);  // xor 4 (row_half_mirror)
  x = dppadd<0x140>(x);  // xor 8 (row_mirror)
  return x;
}
// combine across K-quarters: partners at lane^16 and lane^32
__device__ __forceinline__ float qcomb(float v) {
  v += __shfl_xor(v, 16);
  v += __shfl_xor(v, 32);
  return v;
}

// padded h layout: +4 floats per 32 so the 4 q-groups' broadcast b128 reads
// land on disjoint bank quads. phys(c) = c + 4*(c>>5).
#define HPAD (HDIM + 12)

__global__ __launch_bounds__(NT, 2) void gru_v4(
    const float* __restrict__ xs,       // [B,T,I]
    const float* __restrict__ state,    // [1,B,H]
    const float* __restrict__ alpha_i,  // [B,G]
    const float* __restrict__ beta_i,   // [B,G]
    const float* __restrict__ alpha_h,  // [B,G]
    const float* __restrict__ beta_h,   // [B,G]
    const float* __restrict__ Wx,       // [G,I]
    const float* __restrict__ bx,       // [G]
    const float* __restrict__ Wh,       // [G,H]
    const float* __restrict__ bh,       // [G]
    float* __restrict__ out)            // [B,T,H] then [B,1,H]
{
  __shared__ float lds_h[HPAD];
  __shared__ __align__(16) f32x4 lds_stat[8];  // per-wave {sH,sH2,sI,sI2}

  const int b    = blockIdx.x;
  const int tid  = threadIdx.x;
  const int w    = tid >> 6;
  const int lane = tid & 63;
  const int q    = lane >> 4;            // K-quarter
  const int j    = w * 16 + (lane & 15); // hidden unit

  const int rowR = j, rowI = j + HDIM, rowN = j + 2 * HDIM;

  // ---- persistent weights: 3 rows x 32 cols = 24 f32x4 = 96 VGPRs ----
  f32x4 wr[8], wi[8], wn[8];
  {
    const f32x4* pr = (const f32x4*)(Wh + (size_t)rowR * HDIM + q * 32);
    const f32x4* pi = (const f32x4*)(Wh + (size_t)rowI * HDIM + q * 32);
    const f32x4* pn = (const f32x4*)(Wh + (size_t)rowN * HDIM + q * 32);
#pragma unroll
    for (int k = 0; k < 8; ++k) {
      wr[k] = pr[k]; wi[k] = pi[k]; wn[k] = pn[k];
      // opaque producer: value now comes from asm, not a load -> no remat
      asm volatile("" : "+v"(wr[k]), "+v"(wi[k]), "+v"(wn[k]));
    }
  }
  // Wx rows {R,I,N}, cols [q*4, q*4+4)
  f32x4 wxr = ((const f32x4*)(Wx + (size_t)rowR * IDIM))[q];
  f32x4 wxi = ((const f32x4*)(Wx + (size_t)rowI * IDIM))[q];
  f32x4 wxn = ((const f32x4*)(Wx + (size_t)rowN * IDIM))[q];
  asm volatile("" : "+v"(wxr), "+v"(wxi), "+v"(wxn));

  // ---- per-thread scalars ----
  const float bh_r = bh[rowR], bh_i = bh[rowI], bh_n = bh[rowN];
  const float bx_r = bx[rowR], bx_i = bx[rowI], bx_n = bx[rowN];
  const float ah_r = alpha_h[b * GDIM + rowR];
  const float ah_i = alpha_h[b * GDIM + rowI];
  const float ah_n = alpha_h[b * GDIM + rowN];
  const float bt_r = beta_h[b * GDIM + rowR];
  const float bt_i = beta_h[b * GDIM + rowI];
  const float bt_n = beta_h[b * GDIM + rowN];
  const float ai_r = alpha_i[b * GDIM + rowR];
  const float ai_i = alpha_i[b * GDIM + rowI];
  const float ai_n = alpha_i[b * GDIM + rowN];
  const float bi_r = beta_i[b * GDIM + rowR];
  const float bi_i = beta_i[b * GDIM + rowI];
  const float bi_n = beta_i[b * GDIM + rowN];

  float hreg = state[b * HDIM + j];
  if (lane < 16) lds_h[j + ((j >> 5) << 2)] = hreg;

  const f32x4* xp = (const f32x4*)(xs + (size_t)b * T_STEPS * IDIM);
  float* out_b = out + (size_t)b * T_STEPS * HDIM;

  // x prefetch: this thread's 4 cols for steps t (A) and t+1 (B)
  f32x4 xA = xp[q], xB = xp[4 + q];

  const float invd = 1.f / (float)GDIM;

#define STEP(tcur, X)                                                          \
  do {                                                                         \
    block_barrier(); /* A: h published */                                      \
    const f32x4* hb = (const f32x4*)(lds_h + q * 36);                          \
    f32x4 ar0 = {0.f, 0.f, 0.f, 0.f}, ar1 = ar0;                               \
    f32x4 ai0 = ar0, ai1 = ar0, an0 = ar0, an1 = ar0;                          \
    _Pragma("unroll") for (int k = 0; k < 8; k += 2) {                         \
      f32x4 h0 = hb[k], h1 = hb[k + 1];                                        \
      ar0 = __builtin_elementwise_fma(wr[k], h0, ar0);                         \
      ar1 = __builtin_elementwise_fma(wr[k + 1], h1, ar1);                     \
      ai0 = __builtin_elementwise_fma(wi[k], h0, ai0);                         \
      ai1 = __builtin_elementwise_fma(wi[k + 1], h1, ai1);                     \
      an0 = __builtin_elementwise_fma(wn[k], h0, an0);                         \
      an1 = __builtin_elementwise_fma(wn[k + 1], h1, an1);                     \
    }                                                                          \
    float accr = hsum4(ar0 + ar1);                                             \
    float acci = hsum4(ai0 + ai1);                                             \
    float accn = hsum4(an0 + an1);                                             \
    f32x4 z = {0.f, 0.f, 0.f, 0.f};                                            \
    float aJr = hsum4(__builtin_elementwise_fma(wxr, X, z));                   \
    float aJi = hsum4(__builtin_elementwise_fma(wxi, X, z));                   \
    float aJn = hsum4(__builtin_elementwise_fma(wxn, X, z));                   \
    float Ar = qcomb(accr) + bh_r;                                             \
    float Ai = qcomb(acci) + bh_i;                                             \
    float An = qcomb(accn) + bh_n;                                             \
    float Jr = qcomb(aJr) + bx_r;                                              \
    float Ji = qcomb(aJi) + bx_i;                                              \
    float Jn = qcomb(aJn) + bx_n;                                              \
    f32x4 st = {Ar + Ai + An, Ar * Ar + Ai * Ai + An * An,                     \
                Jr + Ji + Jn, Jr * Jr + Ji * Ji + Jn * Jn};                    \
    st.x = dpp_sum16(st.x); st.y = dpp_sum16(st.y);                            \
    st.z = dpp_sum16(st.z); st.w = dpp_sum16(st.w);                            \
    if (lane == 0) lds_stat[w] = st;                                           \
    block_barrier(); /* B: stats published */                                  \
    f32x4 sT = ((lds_stat[0] + lds_stat[1]) + (lds_stat[2] + lds_stat[3])) +   \
               ((lds_stat[4] + lds_stat[5]) + (lds_stat[6] + lds_stat[7]));    \
    float mH = sT.x * invd;                                                    \
    float rH = rsqrtf(sT.y * invd - mH * mH + LN_EPS);                         \
    float mI = sT.z * invd;                                                    \
    float rI = rsqrtf(sT.w * invd - mI * mI + LN_EPS);                         \
    float hhr = (Ar - mH) * rH * ah_r + bt_r;                                  \
    float hhi = (Ai - mH) * rH * ah_i + bt_i;                                  \
    float hhn = (An - mH) * rH * ah_n + bt_n;                                  \
    float ihr = (Jr - mI) * rI * ai_r + bi_r;                                  \
    float ihi = (Ji - mI) * rI * ai_i + bi_i;                                  \
    float ihn = (Jn - mI) * rI * ai_n + bi_n;                                  \
    float rg = fast_sigmoid(ihr + hhr);                                        \
    float ig = fast_sigmoid(ihi + hhi);                                        \
    float ng = fast_tanh(ihn + rg * hhn);                                      \
    float hy = ng + ig * (hreg - ng);                                          \
    hreg = hy;                                                                 \
    if (lane < 16) {                                                           \
      lds_h[j + ((j >> 5) << 2)] = hy;                                         \
      out_b[(size_t)(tcur) * HDIM + j] = hy;                                   \
    }                                                                          \
    int tn = (tcur) + 2 < T_STEPS ? (tcur) + 2 : T_STEPS - 1;                  \
    X = xp[(size_t)tn * 4 + q];                                                \
  } while (0)

  for (int t = 0; t < T_STEPS; t += 2) {
    STEP(t, xA);
    STEP(t + 1, xB);
  }
#undef STEP

  if (lane < 16)
    out[(size_t)BATCH * T_STEPS * HDIM + b * HDIM + j] = hreg;
}

extern "C" void kernel_launch(void* const* d_in, const int* in_sizes, int n_in,
                              void* d_out, int out_size, void* d_ws, size_t ws_size,
                              hipStream_t stream) {
  const float* xs      = (const float*)d_in[0];
  const float* state   = (const float*)d_in[1];
  const float* alpha_i = (const float*)d_in[2];
  const float* beta_i  = (const float*)d_in[3];
  const float* alpha_h = (const float*)d_in[4];
  const float* beta_h  = (const float*)d_in[5];
  const float* Wx      = (const float*)d_in[6];
  const float* bx      = (const float*)d_in[7];
  const float* Wh      = (const float*)d_in[8];
  const float* bh      = (const float*)d_in[9];
  float* out = (float*)d_out;

  gru_v4<<<dim3(BATCH), dim3(NT), 0, stream>>>(
      xs, state, alpha_i, beta_i, alpha_h, beta_h, Wx, bx, Wh, bh, out);
}

// Round 5
// 9604.045 us; speedup vs baseline: 1.5545x; 1.1551x over previous
//
#include <hip/hip_runtime.h>

// LearnableCell: FiLM'd LayerNorm-GRU, round 5 — MFMA recurrence.
//
// K1 inproj (round-2 verified): ih_all = LN(x@Wx^T+bx)*alpha_i+beta_i -> d_ws.
// K2 gru_mfma: 32 WGs x 256 threads (4 waves). Per chain step, the 384x128
//   matvec runs on the matrix pipe: A = h replicated across rows (16x32 bf16),
//   B = Wh tile (32x16 bf16), C[16x16] cols = outputs. Wave w owns 6 tiles:
//   {gate r,i,n} x {j, j+16} with j = 32w + (lane&15)  -> lane-local gates.
//   Split-bf16 (hi+lo for both h and W, 3 products) keeps fp32-grade accuracy.
//   LDS per step/CU: ~32 A-frag reads + ~16 h writes + ~12 stat ops. 2 barriers.

#define T_STEPS 8192
#define BATCH   32
#define HDIM    128
#define GDIM    384
#define IDIM    16
#define LN_EPS  1e-5f

typedef float f32x2 __attribute__((ext_vector_type(2)));
typedef float f32x4 __attribute__((ext_vector_type(4)));
typedef short bf16x8 __attribute__((ext_vector_type(8)));

__device__ __forceinline__ void block_barrier() {
  asm volatile("s_waitcnt lgkmcnt(0)\n\ts_barrier" ::: "memory");
}
__device__ __forceinline__ float fast_sigmoid(float x) {
  return 1.f / (1.f + __expf(-x));
}
__device__ __forceinline__ float fast_tanh(float x) {
  float e2 = __expf(2.f * x);
  return 1.f - 2.f / (e2 + 1.f);
}
// bf16 (RNE) helpers on raw bits
__device__ __forceinline__ unsigned short f2bf(float x) {
  unsigned u = __float_as_uint(x);
  u += 0x7FFFu + ((u >> 16) & 1u);
  return (unsigned short)(u >> 16);
}
__device__ __forceinline__ float bf2f(unsigned short h) {
  return __uint_as_float(((unsigned)h) << 16);
}

template <int CTRL>
__device__ __forceinline__ float dppadd(float x) {
  return x + __int_as_float(
      __builtin_amdgcn_update_dpp(0, __float_as_int(x), CTRL, 0xF, 0xF, true));
}
__device__ __forceinline__ float dpp_sum16(float x) {
  x = dppadd<0xB1>(x);   // xor 1
  x = dppadd<0x4E>(x);   // xor 2
  x = dppadd<0x141>(x);  // xor 4 (row_half_mirror)
  x = dppadd<0x140>(x);  // xor 8 (row_mirror)
  return x;
}

// ---------------- K1: input projection + LN + FiLM (round-2 verified) --------
__global__ __launch_bounds__(256) void inproj(
    const float* __restrict__ xs, const float* __restrict__ alpha_i,
    const float* __restrict__ beta_i, const float* __restrict__ Wx,
    const float* __restrict__ bx, float* __restrict__ ih_all) {
  const int wid = threadIdx.x >> 6;
  const int lane = threadIdx.x & 63;
  const size_t w = (size_t)blockIdx.x * 4 + wid;
  const int b = (int)(w >> 13);
  const f32x4* xp = (const f32x4*)(xs + w * IDIM);
  f32x4 x0 = xp[0], x1 = xp[1], x2 = xp[2], x3 = xp[3];

  float acc[6];
  float s = 0.f, s2 = 0.f;
#pragma unroll
  for (int k = 0; k < 6; ++k) {
    const int g = k * 64 + lane;
    const f32x4* wp = (const f32x4*)(Wx + (size_t)g * IDIM);
    f32x4 a = __builtin_elementwise_fma(wp[0], x0, (f32x4){0.f, 0.f, 0.f, 0.f});
    a = __builtin_elementwise_fma(wp[1], x1, a);
    a = __builtin_elementwise_fma(wp[2], x2, a);
    a = __builtin_elementwise_fma(wp[3], x3, a);
    float v = bx[g] + ((a.x + a.y) + (a.z + a.w));
    acc[k] = v;
    s += v;
    s2 += v * v;
  }
  s = dpp_sum16(s);  s2 = dpp_sum16(s2);
  s += __shfl_xor(s, 16);  s2 += __shfl_xor(s2, 16);
  s += __shfl_xor(s, 32);  s2 += __shfl_xor(s2, 32);

  const float inv = 1.f / (float)GDIM;
  const float m = s * inv;
  const float r = rsqrtf(s2 * inv - m * m + LN_EPS);

  float* op = ih_all + w * GDIM;
  const float* ai = alpha_i + (size_t)b * GDIM;
  const float* bi = beta_i + (size_t)b * GDIM;
#pragma unroll
  for (int k = 0; k < 6; ++k) {
    const int g = k * 64 + lane;
    op[g] = (acc[k] - m) * r * ai[g] + bi[g];
  }
}

// ---------------- K2: MFMA recurrence ---------------------------------------
__global__ __launch_bounds__(256, 1) void gru_mfma(
    const float* __restrict__ state,    // [1,B,H]
    const float* __restrict__ alpha_h,  // [B,G]
    const float* __restrict__ beta_h,   // [B,G]
    const float* __restrict__ Wh,       // [G,H]
    const float* __restrict__ bh,       // [G]
    const float* __restrict__ ih_all,   // [B,T,G] (precomputed, fp32)
    float* __restrict__ out)            // [B,T,H] then [B,1,H]
{
  __shared__ __align__(16) unsigned short lds_hhi[HDIM];  // h hi bf16
  __shared__ __align__(16) unsigned short lds_hlo[HDIM];  // h lo bf16
  __shared__ __align__(16) f32x2 lds_stat[4];             // per-wave {s, s2}

  const int b    = blockIdx.x;
  const int tid  = threadIdx.x;
  const int w    = tid >> 6;
  const int lane = tid & 63;
  const int c16  = lane & 15;   // output column within tile
  const int kg   = lane >> 4;   // k-subgroup (8 k's per group)
  const int j0   = 32 * w + c16;  // this lane's first hidden unit; second = j0+16

  // tile tt = gate*2 + sub: row = gate*128 + 32*w + sub*16 + c16
  int rows[6];
#pragma unroll
  for (int g3 = 0; g3 < 3; ++g3) {
#pragma unroll
    for (int sub = 0; sub < 2; ++sub)
      rows[g3 * 2 + sub] = g3 * HDIM + 32 * w + sub * 16 + c16;
  }

  // ---- B-frags (weights) : lane supplies B[k = kg*8+e][col=c16] = Wh[row][k]
  bf16x8 Bhi[6][4], Blo[6][4];
#pragma unroll
  for (int tt = 0; tt < 6; ++tt) {
#pragma unroll
    for (int c = 0; c < 4; ++c) {
      const float* wp = Wh + (size_t)rows[tt] * HDIM + c * 32 + kg * 8;
      f32x4 w0 = ((const f32x4*)wp)[0];
      f32x4 w1 = ((const f32x4*)wp)[1];
      bf16x8 hi, lo;
#pragma unroll
      for (int e = 0; e < 4; ++e) {
        unsigned short h0 = f2bf(w0[e]);
        hi[e] = (short)h0;
        lo[e] = (short)f2bf(w0[e] - bf2f(h0));
      }
#pragma unroll
      for (int e = 0; e < 4; ++e) {
        unsigned short h0 = f2bf(w1[e]);
        hi[4 + e] = (short)h0;
        lo[4 + e] = (short)f2bf(w1[e] - bf2f(h0));
      }
      Bhi[tt][c] = hi;
      Blo[tt][c] = lo;
    }
  }

  // ---- per-lane scalars for its 6 rows ----
  float bhv[6], ahv[6], btv[6];
#pragma unroll
  for (int tt = 0; tt < 6; ++tt) {
    bhv[tt] = bh[rows[tt]];
    ahv[tt] = alpha_h[b * GDIM + rows[tt]];
    btv[tt] = beta_h[b * GDIM + rows[tt]];
  }

  // ---- h init ----
  float h0 = state[b * HDIM + j0];
  float h1 = state[b * HDIM + j0 + 16];
  if (lane < 16) {
    unsigned short hh0 = f2bf(h0), hh1 = f2bf(h1);
    lds_hhi[j0] = hh0;
    lds_hhi[j0 + 16] = hh1;
    lds_hlo[j0] = f2bf(h0 - bf2f(hh0));
    lds_hlo[j0 + 16] = f2bf(h1 - bf2f(hh1));
  }

  const float* ih_b = ih_all + (size_t)b * T_STEPS * GDIM;
  float* out_b = out + (size_t)b * T_STEPS * HDIM;

  // ih prefetch pipeline (distance 2)
  float ihA[6], ihB[6];
#pragma unroll
  for (int tt = 0; tt < 6; ++tt) {
    ihA[tt] = ih_b[rows[tt]];
    ihB[tt] = ih_b[GDIM + rows[tt]];
  }

  const float invd = 1.f / (float)GDIM;
  block_barrier();

#define STEP(tcur, IH, H0, H1)                                                 \
  do {                                                                         \
    /* A-frags: lane supplies A[row=c16][k=kg*8+e] = h[k] (replicated) */      \
    bf16x8 Ahi[4], Alo[4];                                                     \
    _Pragma("unroll") for (int c = 0; c < 4; ++c) {                            \
      Ahi[c] = *(const bf16x8*)(&lds_hhi[c * 32 + kg * 8]);                    \
      Alo[c] = *(const bf16x8*)(&lds_hlo[c * 32 + kg * 8]);                    \
    }                                                                          \
    f32x4 C[6];                                                                \
    _Pragma("unroll") for (int tt = 0; tt < 6; ++tt)                           \
        C[tt] = (f32x4){0.f, 0.f, 0.f, 0.f};                                   \
    _Pragma("unroll") for (int c = 0; c < 4; ++c) {                            \
      _Pragma("unroll") for (int tt = 0; tt < 6; ++tt) {                       \
        C[tt] = __builtin_amdgcn_mfma_f32_16x16x32_bf16(Ahi[c], Bhi[tt][c],    \
                                                        C[tt], 0, 0, 0);       \
        C[tt] = __builtin_amdgcn_mfma_f32_16x16x32_bf16(Alo[c], Bhi[tt][c],    \
                                                        C[tt], 0, 0, 0);       \
        C[tt] = __builtin_amdgcn_mfma_f32_16x16x32_bf16(Ahi[c], Blo[tt][c],    \
                                                        C[tt], 0, 0, 0);       \
      }                                                                        \
    }                                                                          \
    float acc[6];                                                              \
    float s = 0.f, s2 = 0.f;                                                   \
    _Pragma("unroll") for (int tt = 0; tt < 6; ++tt) {                         \
      acc[tt] = C[tt][0] + bhv[tt];                                            \
      s += acc[tt];                                                            \
      s2 += acc[tt] * acc[tt];                                                 \
    }                                                                          \
    s = dpp_sum16(s);                                                          \
    s2 = dpp_sum16(s2);                                                        \
    if (lane == 0) lds_stat[w] = (f32x2){s, s2};                               \
    block_barrier(); /* stats + all A-reads done */                            \
    f32x4 p0 = *(const f32x4*)&lds_stat[0];                                    \
    f32x4 p1 = *(const f32x4*)&lds_stat[2];                                    \
    float S = (p0.x + p0.z) + (p1.x + p1.z);                                   \
    float S2 = (p0.y + p0.w) + (p1.y + p1.w);                                  \
    float mH = S * invd;                                                       \
    float rH = rsqrtf(S2 * invd - mH * mH + LN_EPS);                           \
    float hh[6];                                                               \
    _Pragma("unroll") for (int tt = 0; tt < 6; ++tt)                           \
        hh[tt] = (acc[tt] - mH) * rH * ahv[tt] + btv[tt];                      \
    float rg0 = fast_sigmoid(IH[0] + hh[0]);                                   \
    float rg1 = fast_sigmoid(IH[1] + hh[1]);                                   \
    float ig0 = fast_sigmoid(IH[2] + hh[2]);                                   \
    float ig1 = fast_sigmoid(IH[3] + hh[3]);                                   \
    float ng0 = fast_tanh(IH[4] + rg0 * hh[4]);                                \
    float ng1 = fast_tanh(IH[5] + rg1 * hh[5]);                                \
    float hy0 = ng0 + ig0 * (H0 - ng0);                                        \
    float hy1 = ng1 + ig1 * (H1 - ng1);                                        \
    H0 = hy0;                                                                  \
    H1 = hy1;                                                                  \
    if (lane < 16) {                                                           \
      unsigned short q0 = f2bf(hy0), q1 = f2bf(hy1);                           \
      lds_hhi[j0] = q0;                                                        \
      lds_hhi[j0 + 16] = q1;                                                   \
      lds_hlo[j0] = f2bf(hy0 - bf2f(q0));                                      \
      lds_hlo[j0 + 16] = f2bf(hy1 - bf2f(q1));                                 \
      out_b[(size_t)(tcur)*HDIM + j0] = hy0;                                   \
      out_b[(size_t)(tcur)*HDIM + j0 + 16] = hy1;                              \
    }                                                                          \
    int tn = (tcur) + 2 < T_STEPS ? (tcur) + 2 : T_STEPS - 1;                  \
    const float* pp = ih_b + (size_t)tn * GDIM;                                \
    _Pragma("unroll") for (int tt = 0; tt < 6; ++tt) IH[tt] = pp[rows[tt]];    \
    block_barrier(); /* h published */                                         \
  } while (0)

  for (int t = 0; t < T_STEPS; t += 2) {
    STEP(t, ihA, h0, h1);
    STEP(t + 1, ihB, h0, h1);
  }
#undef STEP

  if (lane < 16) {
    out[(size_t)BATCH * T_STEPS * HDIM + b * HDIM + j0] = h0;
    out[(size_t)BATCH * T_STEPS * HDIM + b * HDIM + j0 + 16] = h1;
  }
}

// ---------------- Fallback (round-4, verified) -------------------------------
#define NT 512
#define HPAD (HDIM + 12)
__device__ __forceinline__ float qcomb(float v) {
  v += __shfl_xor(v, 16);
  v += __shfl_xor(v, 32);
  return v;
}
__device__ __forceinline__ float hsum4(f32x4 v) {
  return (v.x + v.y) + (v.z + v.w);
}
__global__ __launch_bounds__(NT, 2) void gru_v4(
    const float* __restrict__ xs, const float* __restrict__ state,
    const float* __restrict__ alpha_i, const float* __restrict__ beta_i,
    const float* __restrict__ alpha_h, const float* __restrict__ beta_h,
    const float* __restrict__ Wx, const float* __restrict__ bx,
    const float* __restrict__ Wh, const float* __restrict__ bh,
    float* __restrict__ out) {
  __shared__ float lds_h[HPAD];
  __shared__ __align__(16) f32x4 lds_stat[8];

  const int b = blockIdx.x;
  const int tid = threadIdx.x;
  const int w = tid >> 6;
  const int lane = tid & 63;
  const int q = lane >> 4;
  const int j = w * 16 + (lane & 15);
  const int rowR = j, rowI = j + HDIM, rowN = j + 2 * HDIM;

  f32x4 wr[8], wi[8], wn[8];
  {
    const f32x4* pr = (const f32x4*)(Wh + (size_t)rowR * HDIM + q * 32);
    const f32x4* pi = (const f32x4*)(Wh + (size_t)rowI * HDIM + q * 32);
    const f32x4* pn = (const f32x4*)(Wh + (size_t)rowN * HDIM + q * 32);
#pragma unroll
    for (int k = 0; k < 8; ++k) {
      wr[k] = pr[k]; wi[k] = pi[k]; wn[k] = pn[k];
      asm volatile("" : "+v"(wr[k]), "+v"(wi[k]), "+v"(wn[k]));
    }
  }
  f32x4 wxr = ((const f32x4*)(Wx + (size_t)rowR * IDIM))[q];
  f32x4 wxi = ((const f32x4*)(Wx + (size_t)rowI * IDIM))[q];
  f32x4 wxn = ((const f32x4*)(Wx + (size_t)rowN * IDIM))[q];
  asm volatile("" : "+v"(wxr), "+v"(wxi), "+v"(wxn));

  const float bh_r = bh[rowR], bh_i = bh[rowI], bh_n = bh[rowN];
  const float bx_r = bx[rowR], bx_i = bx[rowI], bx_n = bx[rowN];
  const float ah_r = alpha_h[b * GDIM + rowR];
  const float ah_i = alpha_h[b * GDIM + rowI];
  const float ah_n = alpha_h[b * GDIM + rowN];
  const float bt_r = beta_h[b * GDIM + rowR];
  const float bt_i = beta_h[b * GDIM + rowI];
  const float bt_n = beta_h[b * GDIM + rowN];
  const float ai_r = alpha_i[b * GDIM + rowR];
  const float ai_i = alpha_i[b * GDIM + rowI];
  const float ai_n = alpha_i[b * GDIM + rowN];
  const float bi_r = beta_i[b * GDIM + rowR];
  const float bi_i = beta_i[b * GDIM + rowI];
  const float bi_n = beta_i[b * GDIM + rowN];

  float hreg = state[b * HDIM + j];
  if (lane < 16) lds_h[j + ((j >> 5) << 2)] = hreg;

  const f32x4* xp = (const f32x4*)(xs + (size_t)b * T_STEPS * IDIM);
  float* out_b = out + (size_t)b * T_STEPS * HDIM;
  f32x4 xA = xp[q], xB = xp[4 + q];
  const float invd = 1.f / (float)GDIM;

#define STEP4(tcur, X)                                                         \
  do {                                                                         \
    block_barrier();                                                           \
    const f32x4* hb = (const f32x4*)(lds_h + q * 36);                          \
    f32x4 ar0 = {0.f, 0.f, 0.f, 0.f}, ar1 = ar0;                               \
    f32x4 ai0 = ar0, ai1 = ar0, an0 = ar0, an1 = ar0;                          \
    _Pragma("unroll") for (int k = 0; k < 8; k += 2) {                         \
      f32x4 h0 = hb[k], h1 = hb[k + 1];                                        \
      ar0 = __builtin_elementwise_fma(wr[k], h0, ar0);                         \
      ar1 = __builtin_elementwise_fma(wr[k + 1], h1, ar1);                     \
      ai0 = __builtin_elementwise_fma(wi[k], h0, ai0);                         \
      ai1 = __builtin_elementwise_fma(wi[k + 1], h1, ai1);                     \
      an0 = __builtin_elementwise_fma(wn[k], h0, an0);                         \
      an1 = __builtin_elementwise_fma(wn[k + 1], h1, an1);                     \
    }                                                                          \
    float accr = hsum4(ar0 + ar1);                                             \
    float acci = hsum4(ai0 + ai1);                                             \
    float accn = hsum4(an0 + an1);                                             \
    f32x4 z = {0.f, 0.f, 0.f, 0.f};                                            \
    float aJr = hsum4(__builtin_elementwise_fma(wxr, X, z));                   \
    float aJi = hsum4(__builtin_elementwise_fma(wxi, X, z));                   \
    float aJn = hsum4(__builtin_elementwise_fma(wxn, X, z));                   \
    float Ar = qcomb(accr) + bh_r;                                             \
    float Ai = qcomb(acci) + bh_i;                                             \
    float An = qcomb(accn) + bh_n;                                             \
    float Jr = qcomb(aJr) + bx_r;                                              \
    float Ji = qcomb(aJi) + bx_i;                                              \
    float Jn = qcomb(aJn) + bx_n;                                              \
    f32x4 st = {Ar + Ai + An, Ar * Ar + Ai * Ai + An * An,                     \
                Jr + Ji + Jn, Jr * Jr + Ji * Ji + Jn * Jn};                    \
    st.x = dpp_sum16(st.x); st.y = dpp_sum16(st.y);                            \
    st.z = dpp_sum16(st.z); st.w = dpp_sum16(st.w);                            \
    if (lane == 0) lds_stat[w] = st;                                           \
    block_barrier();                                                           \
    f32x4 sT = ((lds_stat[0] + lds_stat[1]) + (lds_stat[2] + lds_stat[3])) +   \
               ((lds_stat[4] + lds_stat[5]) + (lds_stat[6] + lds_stat[7]));    \
    float mH = sT.x * invd;                                                    \
    float rH = rsqrtf(sT.y * invd - mH * mH + LN_EPS);                         \
    float mI = sT.z * invd;                                                    \
    float rI = rsqrtf(sT.w * invd - mI * mI + LN_EPS);                         \
    float hhr = (Ar - mH) * rH * ah_r + bt_r;                                  \
    float hhi = (Ai - mH) * rH * ah_i + bt_i;                                  \
    float hhn = (An - mH) * rH * ah_n + bt_n;                                  \
    float ihr = (Jr - mI) * rI * ai_r + bi_r;                                  \
    float ihi = (Ji - mI) * rI * ai_i + bi_i;                                  \
    float ihn = (Jn - mI) * rI * ai_n + bi_n;                                  \
    float rg = fast_sigmoid(ihr + hhr);                                        \
    float ig = fast_sigmoid(ihi + hhi);                                        \
    float ng = fast_tanh(ihn + rg * hhn);                                      \
    float hy = ng + ig * (hreg - ng);                                          \
    hreg = hy;                                                                 \
    if (lane < 16) {                                                           \
      lds_h[j + ((j >> 5) << 2)] = hy;                                         \
      out_b[(size_t)(tcur)*HDIM + j] = hy;                                     \
    }                                                                          \
    int tn = (tcur) + 2 < T_STEPS ? (tcur) + 2 : T_STEPS - 1;                  \
    X = xp[(size_t)tn * 4 + q];                                                \
  } while (0)

  for (int t = 0; t < T_STEPS; t += 2) {
    STEP4(t, xA);
    STEP4(t + 1, xB);
  }
#undef STEP4

  if (lane < 16)
    out[(size_t)BATCH * T_STEPS * HDIM + b * HDIM + j] = hreg;
}

extern "C" void kernel_launch(void* const* d_in, const int* in_sizes, int n_in,
                              void* d_out, int out_size, void* d_ws, size_t ws_size,
                              hipStream_t stream) {
  const float* xs      = (const float*)d_in[0];
  const float* state   = (const float*)d_in[1];
  const float* alpha_i = (const float*)d_in[2];
  const float* beta_i  = (const float*)d_in[3];
  const float* alpha_h = (const float*)d_in[4];
  const float* beta_h  = (const float*)d_in[5];
  const float* Wx      = (const float*)d_in[6];
  const float* bx      = (const float*)d_in[7];
  const float* Wh      = (const float*)d_in[8];
  const float* bh      = (const float*)d_in[9];
  float* out = (float*)d_out;

  const size_t ih_bytes = (size_t)BATCH * T_STEPS * GDIM * sizeof(float);
  if (ws_size >= ih_bytes) {
    float* ih_all = (float*)d_ws;
    inproj<<<dim3(BATCH * T_STEPS / 4), dim3(256), 0, stream>>>(
        xs, alpha_i, beta_i, Wx, bx, ih_all);
    gru_mfma<<<dim3(BATCH), dim3(256), 0, stream>>>(
        state, alpha_h, beta_h, Wh, bh, ih_all, out);
  } else {
    gru_v4<<<dim3(BATCH), dim3(NT), 0, stream>>>(
        xs, state, alpha_i, beta_i, alpha_h, beta_h, Wx, bx, Wh, bh, out);
  }
}